// Round 3
// baseline (361.372 us; speedup 1.0000x reference)
//
#include <hip/hip_runtime.h>
#include <hip/hip_bf16.h>

typedef unsigned short u16;
typedef unsigned int u32;
typedef __attribute__((ext_vector_type(8))) short short8;
typedef __attribute__((ext_vector_type(4))) float f32x4;

#define NN 8192
#define FIN 512
#define FOUT 128
#define NEG 0.2f

__device__ __forceinline__ u16 f2bf(float f) {
  u32 u = __builtin_bit_cast(u32, f);
  u32 r = (u + 0x7fffu + ((u >> 16) & 1u)) >> 16;
  return (u16)r;
}

// K1: h = x @ w (fp32). Also emit Hb bf16 in slot-permuted layout:
// hb[chunk][n][pos] = bf16(h[chunk*128 + j(pos)][n]) with, within each
// 32-block, j(slot) = sigma(slot) = kg*4 + (e&3) + (e>=4)*16 (slot=kg*8+e).
// sigma makes MFMA fragment-order att stores fully dense (64B/row/instr).
__global__ __launch_bounds__(256) void k_h(const float* __restrict__ x,
                                           const float* __restrict__ w,
                                           float* __restrict__ h,
                                           u16* __restrict__ hb) {
  __shared__ float xs[32][68];
  __shared__ float ws_[64][128];
  const int t = threadIdx.x;
  const int r0 = blockIdx.x * 32;
  const int r = t >> 3;
  const int cq = (t & 7) * 4;
  float acc[4][4] = {};
  for (int kc = 0; kc < FIN; kc += 64) {
    __syncthreads();
    {
      const int rr = t >> 3, cc = (t & 7) * 8;
      const float4* src = (const float4*)(x + (size_t)(r0 + rr) * FIN + kc + cc);
      *(float4*)&xs[rr][cc] = src[0];
      *(float4*)&xs[rr][cc + 4] = src[1];
    }
#pragma unroll
    for (int i = 0; i < 8; ++i) {
      const int off = i * 1024 + t * 4;
      const int wr = off >> 7, wc = off & 127;
      *(float4*)&ws_[wr][wc] = *(const float4*)(w + (size_t)(kc + wr) * FOUT + wc);
    }
    __syncthreads();
    for (int kk = 0; kk < 64; ++kk) {
      const float xv = xs[r][kk];
#pragma unroll
      for (int g = 0; g < 4; ++g) {
        const float4 wv = *(const float4*)&ws_[kk][cq + 32 * g];
        acc[g][0] = fmaf(xv, wv.x, acc[g][0]);
        acc[g][1] = fmaf(xv, wv.y, acc[g][1]);
        acc[g][2] = fmaf(xv, wv.z, acc[g][2]);
        acc[g][3] = fmaf(xv, wv.w, acc[g][3]);
      }
    }
  }
  const int rg = r0 + r;
  const int ch = rg >> 7;
  const int jj = rg & 127;
  const int jl = jj & 31;
  const int lo = jl & 15;
  // sigma^-1: slot within 32-block this row lands in
  const int pos = (jj & 96) + ((lo >> 2) << 3) + (lo & 3) + ((jl >> 4) << 2);
#pragma unroll
  for (int g = 0; g < 4; ++g) {
    float4 v;
    v.x = acc[g][0]; v.y = acc[g][1]; v.z = acc[g][2]; v.w = acc[g][3];
    *(float4*)(h + (size_t)rg * FOUT + cq + 32 * g) = v;
#pragma unroll
    for (int e = 0; e < 4; ++e) {
      const int n = cq + 32 * g + e;
      hb[(size_t)ch * 16384 + n * 128 + pos] = f2bf(acc[g][e]);
    }
  }
}

// K2: s = h @ a[:128], t = h @ a[128:].  One wave per row.
__global__ __launch_bounds__(256) void k_scores(const float* __restrict__ h,
                                                const float* __restrict__ a,
                                                float* __restrict__ s,
                                                float* __restrict__ t) {
  const int wid = threadIdx.x >> 6, lane = threadIdx.x & 63;
  const int row = blockIdx.x * 4 + wid;
  const float2 hv = *(const float2*)(h + (size_t)row * FOUT + lane * 2);
  const float2 a0 = *(const float2*)(a + lane * 2);
  const float2 a1 = *(const float2*)(a + FOUT + lane * 2);
  float ps = hv.x * a0.x + hv.y * a0.y;
  float pt = hv.x * a1.x + hv.y * a1.y;
#pragma unroll
  for (int d = 1; d < 64; d <<= 1) {
    ps += __shfl_xor(ps, d);
    pt += __shfl_xor(pt, d);
  }
  if (lane == 0) { s[row] = ps; t[row] = pt; }
}

// K3: tmax = max(t)
__global__ __launch_bounds__(256) void k_tmax(const float* __restrict__ t,
                                              float* __restrict__ tmax) {
  __shared__ float red[256];
  float m = -1e30f;
  for (int i = threadIdx.x; i < NN; i += 256) m = fmaxf(m, t[i]);
  red[threadIdx.x] = m;
  __syncthreads();
  for (int s2 = 128; s2 > 0; s2 >>= 1) {
    if (threadIdx.x < s2) red[threadIdx.x] = fmaxf(red[threadIdx.x], red[threadIdx.x + s2]);
    __syncthreads();
  }
  if (threadIdx.x == 0) tmax[0] = red[0];
}

// K4a: stream adj ONCE. Per row: denominator l_i (safe upper-bound max
// m_i = lrelu(s_i + tmax)) -> linv = 1/l, plus transposed bitmask
// maskT[word][row] (8 MB) so adj is never re-read.
// 16 waves/block, 1 row per wave, 512 blocks -> 8 waves/SIMD.
__global__ __launch_bounds__(1024, 2) void k_mask(const int* __restrict__ adj,
                                                  const float* __restrict__ sg,
                                                  const float* __restrict__ tg,
                                                  const float* __restrict__ tmaxp,
                                                  u32* __restrict__ maskT,
                                                  float* __restrict__ linv) {
  __shared__ u32 mlds[256 * 17];  // [wi][row] pad-17 vs bank conflicts
  const int tid = threadIdx.x;
  const int w = tid >> 6, lane = tid & 63;
  const int r0 = blockIdx.x << 4;
  const int row = r0 + w;
  const float sv = sg[row];
  const float vm = sv + tmaxp[0];
  const float m = fmaxf(vm, NEG * vm);  // lrelu monotone: >= all row entries
  const int4* ap = (const int4*)(adj + (size_t)row * NN);
  float sum = 0.f;
#pragma unroll 4
  for (int it = 0; it < 32; ++it) {
    const int4 a0 = ap[it * 64 + lane];
    const float4 tv = *(const float4*)(tg + it * 256 + lane * 4);
    u32 nib = 0u;
    float e, p, sm = 0.f;
    e = sv + tv.x; e = fmaxf(e, NEG * e); p = __expf(e - m); sm += (a0.x > 0) ? p : 0.f; nib |= (a0.x > 0) ? 1u : 0u;
    e = sv + tv.y; e = fmaxf(e, NEG * e); p = __expf(e - m); sm += (a0.y > 0) ? p : 0.f; nib |= (a0.y > 0) ? 2u : 0u;
    e = sv + tv.z; e = fmaxf(e, NEG * e); p = __expf(e - m); sm += (a0.z > 0) ? p : 0.f; nib |= (a0.z > 0) ? 4u : 0u;
    e = sv + tv.w; e = fmaxf(e, NEG * e); p = __expf(e - m); sm += (a0.w > 0) ? p : 0.f; nib |= (a0.w > 0) ? 8u : 0u;
    sum += sm;
    u32 v0 = nib;
    v0 |= __shfl_xor(v0, 1) << 4;
    v0 |= __shfl_xor(v0, 2) << 8;
    v0 |= __shfl_xor(v0, 4) << 16;
    if ((lane & 7) == 0) mlds[(it * 8 + (lane >> 3)) * 17 + w] = v0;
  }
#pragma unroll
  for (int d = 1; d < 64; d <<= 1) sum += __shfl_xor(sum, d);
  if (lane == 0) linv[row] = 1.0f / sum;
  __syncthreads();
  for (int idx = tid; idx < 4096; idx += 1024) {
    const int wi = idx >> 4, r = idx & 15;
    maskT[(size_t)wi * NN + r0 + r] = mlds[wi * 17 + r];
  }
}

// K4b: barrier-free att + h'. Block = 16 rows, 16 waves each own 512 cols.
// Lane computes p directly in MFMA A-fragment slot order; sigma mapping makes
// both float4 att stores per step dense 64B segments. h' partials merged once
// via LDS atomicAdd.
__global__ __launch_bounds__(1024, 4) void k_attn(const float* __restrict__ sg,
                                                  const float* __restrict__ tg,
                                                  const float* __restrict__ tmaxp,
                                                  const float* __restrict__ linvg,
                                                  const u32* __restrict__ maskT,
                                                  const u16* __restrict__ hb,
                                                  float* __restrict__ att,
                                                  float* __restrict__ hp) {
  __shared__ float hsum[16 * 132];
  __shared__ float s_s[16], s_m[16], s_inv[16];
  const int tid = threadIdx.x;
  const int w = tid >> 6, lane = tid & 63;
  const int arow = lane & 15, kg = lane >> 4;
  const int r0 = blockIdx.x << 4;

  for (int i = tid; i < 16 * 132; i += 1024) hsum[i] = 0.f;
  if (tid < 16) {
    const float sv = sg[r0 + tid];
    const float vm = sv + tmaxp[0];
    s_s[tid] = sv;
    s_m[tid] = fmaxf(vm, NEG * vm);
    s_inv[tid] = linvg[r0 + tid];
  }
  __syncthreads();

  const float sR = s_s[arow], mR = s_m[arow], invR = s_inv[arow];
  f32x4 acc[8];
#pragma unroll
  for (int i = 0; i < 8; ++i) acc[i] = (f32x4){0.f, 0.f, 0.f, 0.f};

#pragma unroll
  for (int ckl = 0; ckl < 4; ++ckl) {
    const int ckg = w * 4 + ckl;
    const u16* hc = hb + (size_t)ckg * 16384;
    const int jb0 = ckg << 7;
#pragma unroll
    for (int ks = 0; ks < 4; ++ks) {
      const u32 wd = maskT[(size_t)(ckg * 4 + ks) * NN + r0 + arow];
      const int jbase = jb0 + ks * 32;
      const float4 ta = *(const float4*)(tg + jbase + kg * 4);
      const float4 tb = *(const float4*)(tg + jbase + 16 + kg * 4);
      const u32 nlo = (wd >> (kg * 4)) & 0xfu;
      const u32 nhi = (wd >> (16 + kg * 4)) & 0xfu;
      float p[8];
      float e;
      e = sR + ta.x; e = fmaxf(e, NEG * e); p[0] = (nlo & 1u) ? __expf(e - mR) * invR : 0.f;
      e = sR + ta.y; e = fmaxf(e, NEG * e); p[1] = (nlo & 2u) ? __expf(e - mR) * invR : 0.f;
      e = sR + ta.z; e = fmaxf(e, NEG * e); p[2] = (nlo & 4u) ? __expf(e - mR) * invR : 0.f;
      e = sR + ta.w; e = fmaxf(e, NEG * e); p[3] = (nlo & 8u) ? __expf(e - mR) * invR : 0.f;
      e = sR + tb.x; e = fmaxf(e, NEG * e); p[4] = (nhi & 1u) ? __expf(e - mR) * invR : 0.f;
      e = sR + tb.y; e = fmaxf(e, NEG * e); p[5] = (nhi & 2u) ? __expf(e - mR) * invR : 0.f;
      e = sR + tb.z; e = fmaxf(e, NEG * e); p[6] = (nhi & 4u) ? __expf(e - mR) * invR : 0.f;
      e = sR + tb.w; e = fmaxf(e, NEG * e); p[7] = (nhi & 8u) ? __expf(e - mR) * invR : 0.f;

      float* op = att + (size_t)(r0 + arow) * NN + jbase;
      float4 o0; o0.x = p[0]; o0.y = p[1]; o0.z = p[2]; o0.w = p[3];
      float4 o1; o1.x = p[4]; o1.y = p[5]; o1.z = p[6]; o1.w = p[7];
      *(float4*)(op + kg * 4) = o0;
      *(float4*)(op + 16 + kg * 4) = o1;

      union { short8 s8; u32 u[4]; } afu;
#pragma unroll
      for (int h2 = 0; h2 < 4; ++h2)
        afu.u[h2] = (u32)f2bf(p[2 * h2]) | ((u32)f2bf(p[2 * h2 + 1]) << 16);
      const int ko = ks * 32 + kg * 8;
#pragma unroll
      for (int nt = 0; nt < 8; ++nt) {
        const short8 bf = *(const short8*)(hc + (nt * 16 + arow) * 128 + ko);
        acc[nt] = __builtin_amdgcn_mfma_f32_16x16x32_bf16(afu.s8, bf, acc[nt], 0, 0, 0);
      }
    }
  }
#pragma unroll
  for (int nt = 0; nt < 8; ++nt)
#pragma unroll
    for (int q = 0; q < 4; ++q)
      atomicAdd(&hsum[(kg * 4 + q) * 132 + nt * 16 + arow], acc[nt][q]);
  __syncthreads();
  for (int i = tid; i < 2048; i += 1024)
    hp[(size_t)(r0 + (i >> 7)) * FOUT + (i & 127)] = hsum[(i >> 7) * 132 + (i & 127)];
}

extern "C" void kernel_launch(void* const* d_in, const int* in_sizes, int n_in,
                              void* d_out, int out_size, void* d_ws, size_t ws_size,
                              hipStream_t stream) {
  const float* x = (const float*)d_in[0];
  const int* adj = (const int*)d_in[1];
  const float* w = (const float*)d_in[2];
  const float* a = (const float*)d_in[3];
  float* out = (float*)d_out;
  float* att = out;
  float* hp = out + (size_t)NN * NN;    // h' slot
  float* h = hp;                        // fp32 h scratch (consumed before K4b writes)
  u16* hb = (u16*)d_ws;                 // [0, 2MB) slot-permuted bf16 h
  float* s = (float*)((char*)d_ws + (size_t)2 * 1024 * 1024);
  float* t = s + NN;
  float* linv = t + NN;
  float* tmax = linv + NN;
  u32* maskT = (u32*)((char*)d_ws + (size_t)4 * 1024 * 1024);  // [4MB, 12MB)

  k_h<<<256, 256, 0, stream>>>(x, w, h, hb);
  k_scores<<<2048, 256, 0, stream>>>(h, a, s, t);
  k_tmax<<<1, 256, 0, stream>>>(t, tmax);
  k_mask<<<512, 1024, 0, stream>>>(adj, s, t, tmax, maskT, linv);
  k_attn<<<512, 1024, 0, stream>>>(s, t, tmax, linv, maskT, hb, att, hp);
}

// Round 4
// 351.970 us; speedup vs baseline: 1.0267x; 1.0267x over previous
//
#include <hip/hip_runtime.h>
#include <hip/hip_bf16.h>

typedef unsigned short u16;
typedef unsigned int u32;
typedef __attribute__((ext_vector_type(8))) short short8;
typedef __attribute__((ext_vector_type(4))) float f32x4;

#define NN 8192
#define FIN 512
#define FOUT 128
#define NEG 0.2f

__device__ __forceinline__ u16 f2bf(float f) {
  u32 u = __builtin_bit_cast(u32, f);
  u32 r = (u + 0x7fffu + ((u >> 16) & 1u)) >> 16;
  return (u16)r;
}

// K1: h = x @ w. Emits (a) hb: bf16 h in slot-permuted layout
// hb[chunk][n][pos], pos = sigma^-1(row within 128) so that MFMA
// fragment-order att stores are dense; (b) s,t scores directly
// (8-lane in-wave reduction) — no fp32 h buffer at all.
__global__ __launch_bounds__(256) void k_h(const float* __restrict__ x,
                                           const float* __restrict__ w,
                                           const float* __restrict__ av,
                                           u16* __restrict__ hb,
                                           float* __restrict__ sg,
                                           float* __restrict__ tgo) {
  __shared__ float xs[32][68];
  __shared__ float ws_[64][128];
  const int t = threadIdx.x;
  const int r0 = blockIdx.x * 32;
  const int r = t >> 3;
  const int cq = (t & 7) * 4;
  float acc[4][4] = {};
  for (int kc = 0; kc < FIN; kc += 64) {
    __syncthreads();
    {
      const int rr = t >> 3, cc = (t & 7) * 8;
      const float4* src = (const float4*)(x + (size_t)(r0 + rr) * FIN + kc + cc);
      *(float4*)&xs[rr][cc] = src[0];
      *(float4*)&xs[rr][cc + 4] = src[1];
    }
#pragma unroll
    for (int i = 0; i < 8; ++i) {
      const int off = i * 1024 + t * 4;
      const int wr = off >> 7, wc = off & 127;
      *(float4*)&ws_[wr][wc] = *(const float4*)(w + (size_t)(kc + wr) * FOUT + wc);
    }
    __syncthreads();
    for (int kk = 0; kk < 64; ++kk) {
      const float xv = xs[r][kk];
#pragma unroll
      for (int g = 0; g < 4; ++g) {
        const float4 wv = *(const float4*)&ws_[kk][cq + 32 * g];
        acc[g][0] = fmaf(xv, wv.x, acc[g][0]);
        acc[g][1] = fmaf(xv, wv.y, acc[g][1]);
        acc[g][2] = fmaf(xv, wv.z, acc[g][2]);
        acc[g][3] = fmaf(xv, wv.w, acc[g][3]);
      }
    }
  }
  const int rg = r0 + r;
  const int ch = rg >> 7;
  const int jj = rg & 127;
  const int jl = jj & 31;
  const int lo = jl & 15;
  const int pos = (jj & 96) + ((lo >> 2) << 3) + (lo & 3) + ((jl >> 4) << 2);
  float sp = 0.f, tp = 0.f;
#pragma unroll
  for (int g = 0; g < 4; ++g) {
#pragma unroll
    for (int e = 0; e < 4; ++e) {
      const int n = cq + 32 * g + e;
      const float v = acc[g][e];
      hb[(size_t)ch * 16384 + n * 128 + pos] = f2bf(v);
      sp = fmaf(v, av[n], sp);
      tp = fmaf(v, av[FOUT + n], tp);
    }
  }
#pragma unroll
  for (int d = 1; d < 8; d <<= 1) {
    sp += __shfl_xor(sp, d);
    tp += __shfl_xor(tp, d);
  }
  if ((t & 7) == 0) { sg[rg] = sp; tgo[rg] = tp; }
}

// K2: tmax = max(t)
__global__ __launch_bounds__(256) void k_tmax(const float* __restrict__ t,
                                              float* __restrict__ tmax) {
  __shared__ float red[256];
  float m = -1e30f;
  for (int i = threadIdx.x; i < NN; i += 256) m = fmaxf(m, t[i]);
  red[threadIdx.x] = m;
  __syncthreads();
  for (int s2 = 128; s2 > 0; s2 >>= 1) {
    if (threadIdx.x < s2) red[threadIdx.x] = fmaxf(red[threadIdx.x], red[threadIdx.x + s2]);
    __syncthreads();
  }
  if (threadIdx.x == 0) tmax[0] = red[0];
}

// K3: stream adj ONCE. Per row: denominator -> linv = 1/l (safe upper-bound
// max m_i = lrelu(s_i + tmax)), plus transposed bitmask maskT[word][row].
__global__ __launch_bounds__(1024, 2) void k_mask(const int* __restrict__ adj,
                                                  const float* __restrict__ sg,
                                                  const float* __restrict__ tg,
                                                  const float* __restrict__ tmaxp,
                                                  u32* __restrict__ maskT,
                                                  float* __restrict__ linv) {
  __shared__ u32 mlds[256 * 17];
  const int tid = threadIdx.x;
  const int w = tid >> 6, lane = tid & 63;
  const int r0 = blockIdx.x << 4;
  const int row = r0 + w;
  const float sv = sg[row];
  const float vm = sv + tmaxp[0];
  const float m = fmaxf(vm, NEG * vm);
  const int4* ap = (const int4*)(adj + (size_t)row * NN);
  float sum = 0.f;
#pragma unroll 4
  for (int it = 0; it < 32; ++it) {
    const int4 a0 = ap[it * 64 + lane];
    const float4 tv = *(const float4*)(tg + it * 256 + lane * 4);
    u32 nib = 0u;
    float e, p, sm = 0.f;
    e = sv + tv.x; e = fmaxf(e, NEG * e); p = __expf(e - m); sm += (a0.x > 0) ? p : 0.f; nib |= (a0.x > 0) ? 1u : 0u;
    e = sv + tv.y; e = fmaxf(e, NEG * e); p = __expf(e - m); sm += (a0.y > 0) ? p : 0.f; nib |= (a0.y > 0) ? 2u : 0u;
    e = sv + tv.z; e = fmaxf(e, NEG * e); p = __expf(e - m); sm += (a0.z > 0) ? p : 0.f; nib |= (a0.z > 0) ? 4u : 0u;
    e = sv + tv.w; e = fmaxf(e, NEG * e); p = __expf(e - m); sm += (a0.w > 0) ? p : 0.f; nib |= (a0.w > 0) ? 8u : 0u;
    sum += sm;
    u32 v0 = nib;
    v0 |= __shfl_xor(v0, 1) << 4;
    v0 |= __shfl_xor(v0, 2) << 8;
    v0 |= __shfl_xor(v0, 4) << 16;
    if ((lane & 7) == 0) mlds[(it * 8 + (lane >> 3)) * 17 + w] = v0;
  }
#pragma unroll
  for (int d = 1; d < 64; d <<= 1) sum += __shfl_xor(sum, d);
  if (lane == 0) linv[row] = 1.0f / sum;
  __syncthreads();
  for (int idx = tid; idx < 4096; idx += 1024) {
    const int wi = idx >> 4, r = idx & 15;
    maskT[(size_t)wi * NN + r0 + r] = mlds[wi * 17 + r];
  }
}

// K4: att + h'. Block = 32 rows (16 waves), wave = 32 rows x 512 cols.
// Each lane computes p in MFMA A-fragment slot order for TWO row-groups;
// hb B-fragments are loaded once and reused by both (16 MFMA / 8 loads).
// sigma layout makes both float4 att stores per row dense 64B halves of one
// 128B line. h' partials merged once via LDS atomicAdd.
__global__ __launch_bounds__(1024, 4) void k_att(const float* __restrict__ sg,
                                                 const float* __restrict__ tg,
                                                 const float* __restrict__ tmaxp,
                                                 const float* __restrict__ linvg,
                                                 const u32* __restrict__ maskT,
                                                 const u16* __restrict__ hb,
                                                 float* __restrict__ att,
                                                 float* __restrict__ hp) {
  __shared__ float hsum[32 * 132];
  const int tid = threadIdx.x;
  const int w = tid >> 6, lane = tid & 63;
  const int arow = lane & 15, kg = lane >> 4;
  const int R0 = blockIdx.x << 5;

  for (int i = tid; i < 32 * 132; i += 1024) hsum[i] = 0.f;
  __syncthreads();

  const int row0 = R0 + arow, row1 = row0 + 16;
  const float tm = tmaxp[0];
  const float s0 = sg[row0], s1 = sg[row1];
  const float inv0 = linvg[row0], inv1 = linvg[row1];
  const float vm0 = s0 + tm, vm1 = s1 + tm;
  const float m0 = fmaxf(vm0, NEG * vm0), m1 = fmaxf(vm1, NEG * vm1);

  f32x4 acc0[8], acc1[8];
#pragma unroll
  for (int i = 0; i < 8; ++i) {
    acc0[i] = (f32x4){0.f, 0.f, 0.f, 0.f};
    acc1[i] = (f32x4){0.f, 0.f, 0.f, 0.f};
  }

  const int w4 = w * 4;
  for (int ckl = 0; ckl < 4; ++ckl) {
    const int ckg = w4 + ckl;
    const u16* hc = hb + (size_t)ckg * 16384;
    const int jb0 = ckg << 7;
#pragma unroll
    for (int ks = 0; ks < 4; ++ks) {
      const int jbase = jb0 + ks * 32;
      const u32 wd0 = maskT[(size_t)(ckg * 4 + ks) * NN + row0];
      const u32 wd1 = maskT[(size_t)(ckg * 4 + ks) * NN + row1];
      const float4 ta = *(const float4*)(tg + jbase + kg * 4);
      const float4 tb = *(const float4*)(tg + jbase + 16 + kg * 4);
      union { short8 s8; u32 u[4]; } af0, af1;
      {
        const u32 nlo = (wd0 >> (kg * 4)) & 0xfu;
        const u32 nhi = (wd0 >> (16 + kg * 4)) & 0xfu;
        float p[8], e;
        e = s0 + ta.x; e = fmaxf(e, NEG * e); p[0] = (nlo & 1u) ? __expf(e - m0) * inv0 : 0.f;
        e = s0 + ta.y; e = fmaxf(e, NEG * e); p[1] = (nlo & 2u) ? __expf(e - m0) * inv0 : 0.f;
        e = s0 + ta.z; e = fmaxf(e, NEG * e); p[2] = (nlo & 4u) ? __expf(e - m0) * inv0 : 0.f;
        e = s0 + ta.w; e = fmaxf(e, NEG * e); p[3] = (nlo & 8u) ? __expf(e - m0) * inv0 : 0.f;
        e = s0 + tb.x; e = fmaxf(e, NEG * e); p[4] = (nhi & 1u) ? __expf(e - m0) * inv0 : 0.f;
        e = s0 + tb.y; e = fmaxf(e, NEG * e); p[5] = (nhi & 2u) ? __expf(e - m0) * inv0 : 0.f;
        e = s0 + tb.z; e = fmaxf(e, NEG * e); p[6] = (nhi & 4u) ? __expf(e - m0) * inv0 : 0.f;
        e = s0 + tb.w; e = fmaxf(e, NEG * e); p[7] = (nhi & 8u) ? __expf(e - m0) * inv0 : 0.f;
        float* op = att + (size_t)row0 * NN + jbase;
        float4 o0; o0.x = p[0]; o0.y = p[1]; o0.z = p[2]; o0.w = p[3];
        float4 o1; o1.x = p[4]; o1.y = p[5]; o1.z = p[6]; o1.w = p[7];
        *(float4*)(op + kg * 4) = o0;
        *(float4*)(op + 16 + kg * 4) = o1;
#pragma unroll
        for (int h2 = 0; h2 < 4; ++h2)
          af0.u[h2] = (u32)f2bf(p[2 * h2]) | ((u32)f2bf(p[2 * h2 + 1]) << 16);
      }
      {
        const u32 nlo = (wd1 >> (kg * 4)) & 0xfu;
        const u32 nhi = (wd1 >> (16 + kg * 4)) & 0xfu;
        float p[8], e;
        e = s1 + ta.x; e = fmaxf(e, NEG * e); p[0] = (nlo & 1u) ? __expf(e - m1) * inv1 : 0.f;
        e = s1 + ta.y; e = fmaxf(e, NEG * e); p[1] = (nlo & 2u) ? __expf(e - m1) * inv1 : 0.f;
        e = s1 + ta.z; e = fmaxf(e, NEG * e); p[2] = (nlo & 4u) ? __expf(e - m1) * inv1 : 0.f;
        e = s1 + ta.w; e = fmaxf(e, NEG * e); p[3] = (nlo & 8u) ? __expf(e - m1) * inv1 : 0.f;
        e = s1 + tb.x; e = fmaxf(e, NEG * e); p[4] = (nhi & 1u) ? __expf(e - m1) * inv1 : 0.f;
        e = s1 + tb.y; e = fmaxf(e, NEG * e); p[5] = (nhi & 2u) ? __expf(e - m1) * inv1 : 0.f;
        e = s1 + tb.z; e = fmaxf(e, NEG * e); p[6] = (nhi & 4u) ? __expf(e - m1) * inv1 : 0.f;
        e = s1 + tb.w; e = fmaxf(e, NEG * e); p[7] = (nhi & 8u) ? __expf(e - m1) * inv1 : 0.f;
        float* op = att + (size_t)row1 * NN + jbase;
        float4 o0; o0.x = p[0]; o0.y = p[1]; o0.z = p[2]; o0.w = p[3];
        float4 o1; o1.x = p[4]; o1.y = p[5]; o1.z = p[6]; o1.w = p[7];
        *(float4*)(op + kg * 4) = o0;
        *(float4*)(op + 16 + kg * 4) = o1;
#pragma unroll
        for (int h2 = 0; h2 < 4; ++h2)
          af1.u[h2] = (u32)f2bf(p[2 * h2]) | ((u32)f2bf(p[2 * h2 + 1]) << 16);
      }
      const int ko = ks * 32 + kg * 8;
#pragma unroll
      for (int nt = 0; nt < 4; ++nt) {
        const short8 bf = *(const short8*)(hc + (nt * 16 + arow) * 128 + ko);
        acc0[nt] = __builtin_amdgcn_mfma_f32_16x16x32_bf16(af0.s8, bf, acc0[nt], 0, 0, 0);
        acc1[nt] = __builtin_amdgcn_mfma_f32_16x16x32_bf16(af1.s8, bf, acc1[nt], 0, 0, 0);
      }
#pragma unroll
      for (int nt = 4; nt < 8; ++nt) {
        const short8 bf = *(const short8*)(hc + (nt * 16 + arow) * 128 + ko);
        acc0[nt] = __builtin_amdgcn_mfma_f32_16x16x32_bf16(af0.s8, bf, acc0[nt], 0, 0, 0);
        acc1[nt] = __builtin_amdgcn_mfma_f32_16x16x32_bf16(af1.s8, bf, acc1[nt], 0, 0, 0);
      }
    }
  }
#pragma unroll
  for (int nt = 0; nt < 8; ++nt)
#pragma unroll
    for (int q = 0; q < 4; ++q) {
      atomicAdd(&hsum[(kg * 4 + q) * 132 + nt * 16 + arow], acc0[nt][q]);
      atomicAdd(&hsum[(16 + kg * 4 + q) * 132 + nt * 16 + arow], acc1[nt][q]);
    }
  __syncthreads();
  for (int i = tid; i < 4096; i += 1024)
    hp[(size_t)(R0 + (i >> 7)) * FOUT + (i & 127)] = hsum[(i >> 7) * 132 + (i & 127)];
}

extern "C" void kernel_launch(void* const* d_in, const int* in_sizes, int n_in,
                              void* d_out, int out_size, void* d_ws, size_t ws_size,
                              hipStream_t stream) {
  const float* x = (const float*)d_in[0];
  const int* adj = (const int*)d_in[1];
  const float* w = (const float*)d_in[2];
  const float* a = (const float*)d_in[3];
  float* out = (float*)d_out;
  float* att = out;
  float* hp = out + (size_t)NN * NN;
  u16* hb = (u16*)d_ws;                                        // [0, 2MB)
  float* s = (float*)((char*)d_ws + (size_t)2 * 1024 * 1024);  // 32 KB
  float* t = s + NN;
  float* linv = t + NN;
  float* tmax = linv + NN;
  u32* maskT = (u32*)((char*)d_ws + (size_t)4 * 1024 * 1024);  // [4MB, 12MB)

  k_h<<<256, 256, 0, stream>>>(x, w, a, hb, s, t);
  k_tmax<<<1, 256, 0, stream>>>(t, tmax);
  k_mask<<<512, 1024, 0, stream>>>(adj, s, t, tmax, maskT, linv);
  k_att<<<256, 1024, 0, stream>>>(s, t, tmax, linv, maskT, hb, att, hp);
}

// Round 6
// 265.851 us; speedup vs baseline: 1.3593x; 1.3239x over previous
//
#include <hip/hip_runtime.h>
#include <hip/hip_bf16.h>

typedef unsigned short u16;
typedef unsigned int u32;
typedef __attribute__((ext_vector_type(8))) short short8;
typedef __attribute__((ext_vector_type(4))) float f32x4;
typedef __attribute__((ext_vector_type(4))) int i32x4;

#define NN 8192
#define FIN 512
#define FOUT 128
#define NEG 0.2f
#define L2E 1.44269504088896340736f
#define EXP2(x) __builtin_amdgcn_exp2f(x)
#define LOG2(x) __builtin_amdgcn_logf(x)

__device__ __forceinline__ u16 f2bf(float f) {
  u32 u = __builtin_bit_cast(u32, f);
  u32 r = (u + 0x7fffu + ((u >> 16) & 1u)) >> 16;
  return (u16)r;
}

// K1: h = x @ w. Emits hb (bf16, slot-permuted layout for dense fragment-order
// att stores) and s,t scores directly. No fp32 h buffer.
__global__ __launch_bounds__(256) void k_h(const float* __restrict__ x,
                                           const float* __restrict__ w,
                                           const float* __restrict__ av,
                                           u16* __restrict__ hb,
                                           float* __restrict__ sg,
                                           float* __restrict__ tgo) {
  __shared__ float xs[32][68];
  __shared__ float ws_[64][128];
  const int t = threadIdx.x;
  const int r0 = blockIdx.x * 32;
  const int r = t >> 3;
  const int cq = (t & 7) * 4;
  float acc[4][4] = {};
  for (int kc = 0; kc < FIN; kc += 64) {
    __syncthreads();
    {
      const int rr = t >> 3, cc = (t & 7) * 8;
      const float4* src = (const float4*)(x + (size_t)(r0 + rr) * FIN + kc + cc);
      *(float4*)&xs[rr][cc] = src[0];
      *(float4*)&xs[rr][cc + 4] = src[1];
    }
#pragma unroll
    for (int i = 0; i < 8; ++i) {
      const int off = i * 1024 + t * 4;
      const int wr = off >> 7, wc = off & 127;
      *(float4*)&ws_[wr][wc] = *(const float4*)(w + (size_t)(kc + wr) * FOUT + wc);
    }
    __syncthreads();
    for (int kk = 0; kk < 64; ++kk) {
      const float xv = xs[r][kk];
#pragma unroll
      for (int g = 0; g < 4; ++g) {
        const float4 wv = *(const float4*)&ws_[kk][cq + 32 * g];
        acc[g][0] = fmaf(xv, wv.x, acc[g][0]);
        acc[g][1] = fmaf(xv, wv.y, acc[g][1]);
        acc[g][2] = fmaf(xv, wv.z, acc[g][2]);
        acc[g][3] = fmaf(xv, wv.w, acc[g][3]);
      }
    }
  }
  const int rg = r0 + r;
  const int ch = rg >> 7;
  const int jj = rg & 127;
  const int jl = jj & 31;
  const int lo = jl & 15;
  const int pos = (jj & 96) + ((lo >> 2) << 3) + (lo & 3) + ((jl >> 4) << 2);
  float sp = 0.f, tp = 0.f;
#pragma unroll
  for (int g = 0; g < 4; ++g) {
#pragma unroll
    for (int e = 0; e < 4; ++e) {
      const int n = cq + 32 * g + e;
      const float v = acc[g][e];
      hb[(size_t)ch * 16384 + n * 128 + pos] = f2bf(v);
      sp = fmaf(v, av[n], sp);
      tp = fmaf(v, av[FOUT + n], tp);
    }
  }
#pragma unroll
  for (int d = 1; d < 8; d <<= 1) {
    sp += __shfl_xor(sp, d);
    tp += __shfl_xor(tp, d);
  }
  if ((t & 7) == 0) { sg[rg] = sp; tgo[rg] = tp; }
}

// K2: tmax = max(t)
__global__ __launch_bounds__(256) void k_tmax(const float* __restrict__ t,
                                              float* __restrict__ tmax) {
  __shared__ float red[256];
  float m = -1e30f;
  for (int i = threadIdx.x; i < NN; i += 256) m = fmaxf(m, t[i]);
  red[threadIdx.x] = m;
  __syncthreads();
  for (int s2 = 128; s2 > 0; s2 >>= 1) {
    if (threadIdx.x < s2) red[threadIdx.x] = fmaxf(red[threadIdx.x], red[threadIdx.x + s2]);
    __syncthreads();
  }
  if (threadIdx.x == 0) tmax[0] = red[0];
}

// K3: stream adj ONCE (non-temporal). Per row: transposed bitmask
// maskT[word][row], and folded softmax constant
// c2[row] = -(m*log2e + log2(l))  so  p = exp2(lrelu*L2E + c2).
__global__ __launch_bounds__(1024, 2) void k_mask(const int* __restrict__ adj,
                                                  const float* __restrict__ sg,
                                                  const float* __restrict__ tg,
                                                  const float* __restrict__ tmaxp,
                                                  u32* __restrict__ maskT,
                                                  float* __restrict__ c2g) {
  __shared__ u32 mlds[256 * 17];
  const int tid = threadIdx.x;
  const int w = tid >> 6, lane = tid & 63;
  const int r0 = blockIdx.x << 4;
  const int row = r0 + w;
  const float sv = sg[row];
  const float vm = sv + tmaxp[0];
  const float m = fmaxf(vm, NEG * vm);
  const float m2 = m * L2E;
  const i32x4* ap = (const i32x4*)(adj + (size_t)row * NN);
  float sum = 0.f;
#pragma unroll 4
  for (int it = 0; it < 32; ++it) {
    const i32x4 a0 = __builtin_nontemporal_load(ap + it * 64 + lane);
    const f32x4 tv = *(const f32x4*)(tg + it * 256 + lane * 4);
    u32 nib = 0u;
    float e, p, sm = 0.f;
    e = sv + tv.x; e = fmaxf(e, NEG * e); p = EXP2(fmaf(e, L2E, -m2)); sm += (a0.x > 0) ? p : 0.f; nib |= (a0.x > 0) ? 1u : 0u;
    e = sv + tv.y; e = fmaxf(e, NEG * e); p = EXP2(fmaf(e, L2E, -m2)); sm += (a0.y > 0) ? p : 0.f; nib |= (a0.y > 0) ? 2u : 0u;
    e = sv + tv.z; e = fmaxf(e, NEG * e); p = EXP2(fmaf(e, L2E, -m2)); sm += (a0.z > 0) ? p : 0.f; nib |= (a0.z > 0) ? 4u : 0u;
    e = sv + tv.w; e = fmaxf(e, NEG * e); p = EXP2(fmaf(e, L2E, -m2)); sm += (a0.w > 0) ? p : 0.f; nib |= (a0.w > 0) ? 8u : 0u;
    sum += sm;
    u32 v0 = nib;
    v0 |= __shfl_xor(v0, 1) << 4;
    v0 |= __shfl_xor(v0, 2) << 8;
    v0 |= __shfl_xor(v0, 4) << 16;
    if ((lane & 7) == 0) mlds[(it * 8 + (lane >> 3)) * 17 + w] = v0;
  }
#pragma unroll
  for (int d = 1; d < 64; d <<= 1) sum += __shfl_xor(sum, d);
  if (lane == 0) c2g[row] = -(m2 + LOG2(sum));
  __syncthreads();
  for (int idx = tid; idx < 4096; idx += 1024) {
    const int wi = idx >> 4, r = idx & 15;
    maskT[(size_t)wi * NN + r0 + r] = mlds[wi * 17 + r];
  }
}

// K4: att + h'. 256 blocks x 512 thr (8 waves, 2 waves/SIMD, 256-VGPR budget).
// Block = 32 rows; wave = 32 rows x 1024 cols (8 chunks x 4 ks = 32 steps).
// Explicit depth-1 software pipeline: step k+1's maskT/t/hb loads issue before
// step k's VALU+MFMA. Fragment-order p compute; NT att stores; LDS-atomic merge.
struct StepT {
  u32 wd0, wd1;
  f32x4 ta, tb;
  short8 h0, h1, h2, h3, h4, h5, h6, h7;
};

#define LOADSTEP(st, S)                                                        \
  {                                                                            \
    const int ckg_ = w8 + ((st) >> 2);                                         \
    const int ks_ = (st) & 3;                                                  \
    const int jb_ = (ckg_ << 7) + ks_ * 32;                                    \
    const u32* mp_ = maskT + (size_t)(ckg_ * 4 + ks_) * NN;                    \
    S.wd0 = __builtin_nontemporal_load(mp_ + row0);                            \
    S.wd1 = __builtin_nontemporal_load(mp_ + row1);                            \
    S.ta = *(const f32x4*)(tg + jb_ + kg * 4);                                 \
    S.tb = *(const f32x4*)(tg + jb_ + 16 + kg * 4);                            \
    const u16* hc_ = hb + (size_t)ckg_ * 16384 + arow * 128 + ks_ * 32 + kg * 8; \
    S.h0 = *(const short8*)(hc_);                                              \
    S.h1 = *(const short8*)(hc_ + 2048);                                       \
    S.h2 = *(const short8*)(hc_ + 4096);                                       \
    S.h3 = *(const short8*)(hc_ + 6144);                                       \
    S.h4 = *(const short8*)(hc_ + 8192);                                       \
    S.h5 = *(const short8*)(hc_ + 10240);                                      \
    S.h6 = *(const short8*)(hc_ + 12288);                                      \
    S.h7 = *(const short8*)(hc_ + 14336);                                      \
  }

#define PGROUP(sv, cv, wd, afu, rowbase)                                       \
  {                                                                            \
    const u32 nlo = ((wd) >> (kg * 4)) & 0xfu;                                 \
    const u32 nhi = ((wd) >> (16 + kg * 4)) & 0xfu;                            \
    float p[8], e;                                                             \
    e = (sv) + S.ta.x; e = fmaxf(e, NEG * e); p[0] = (nlo & 1u) ? EXP2(fmaf(e, L2E, (cv))) : 0.f; \
    e = (sv) + S.ta.y; e = fmaxf(e, NEG * e); p[1] = (nlo & 2u) ? EXP2(fmaf(e, L2E, (cv))) : 0.f; \
    e = (sv) + S.ta.z; e = fmaxf(e, NEG * e); p[2] = (nlo & 4u) ? EXP2(fmaf(e, L2E, (cv))) : 0.f; \
    e = (sv) + S.ta.w; e = fmaxf(e, NEG * e); p[3] = (nlo & 8u) ? EXP2(fmaf(e, L2E, (cv))) : 0.f; \
    e = (sv) + S.tb.x; e = fmaxf(e, NEG * e); p[4] = (nhi & 1u) ? EXP2(fmaf(e, L2E, (cv))) : 0.f; \
    e = (sv) + S.tb.y; e = fmaxf(e, NEG * e); p[5] = (nhi & 2u) ? EXP2(fmaf(e, L2E, (cv))) : 0.f; \
    e = (sv) + S.tb.z; e = fmaxf(e, NEG * e); p[6] = (nhi & 4u) ? EXP2(fmaf(e, L2E, (cv))) : 0.f; \
    e = (sv) + S.tb.w; e = fmaxf(e, NEG * e); p[7] = (nhi & 8u) ? EXP2(fmaf(e, L2E, (cv))) : 0.f; \
    f32x4 o0 = {p[0], p[1], p[2], p[3]};                                       \
    f32x4 o1 = {p[4], p[5], p[6], p[7]};                                       \
    float* op_ = att + (size_t)(rowbase)*NN + jb_;                             \
    __builtin_nontemporal_store(o0, (f32x4*)(op_ + kg * 4));                   \
    __builtin_nontemporal_store(o1, (f32x4*)(op_ + 16 + kg * 4));              \
    afu.u[0] = (u32)f2bf(p[0]) | ((u32)f2bf(p[1]) << 16);                      \
    afu.u[1] = (u32)f2bf(p[2]) | ((u32)f2bf(p[3]) << 16);                      \
    afu.u[2] = (u32)f2bf(p[4]) | ((u32)f2bf(p[5]) << 16);                      \
    afu.u[3] = (u32)f2bf(p[6]) | ((u32)f2bf(p[7]) << 16);                      \
  }

#define BODYSTEP(st, S)                                                        \
  {                                                                            \
    const int ckg_ = w8 + ((st) >> 2);                                         \
    const int ks_ = (st) & 3;                                                  \
    const int jb_ = (ckg_ << 7) + ks_ * 32;                                    \
    union { short8 s8; u32 u[4]; } af0, af1;                                   \
    PGROUP(s0, c0, S.wd0, af0, row0);                                          \
    PGROUP(s1, c1r, S.wd1, af1, row1);                                         \
    acc0[0] = __builtin_amdgcn_mfma_f32_16x16x32_bf16(af0.s8, S.h0, acc0[0], 0, 0, 0); \
    acc1[0] = __builtin_amdgcn_mfma_f32_16x16x32_bf16(af1.s8, S.h0, acc1[0], 0, 0, 0); \
    acc0[1] = __builtin_amdgcn_mfma_f32_16x16x32_bf16(af0.s8, S.h1, acc0[1], 0, 0, 0); \
    acc1[1] = __builtin_amdgcn_mfma_f32_16x16x32_bf16(af1.s8, S.h1, acc1[1], 0, 0, 0); \
    acc0[2] = __builtin_amdgcn_mfma_f32_16x16x32_bf16(af0.s8, S.h2, acc0[2], 0, 0, 0); \
    acc1[2] = __builtin_amdgcn_mfma_f32_16x16x32_bf16(af1.s8, S.h2, acc1[2], 0, 0, 0); \
    acc0[3] = __builtin_amdgcn_mfma_f32_16x16x32_bf16(af0.s8, S.h3, acc0[3], 0, 0, 0); \
    acc1[3] = __builtin_amdgcn_mfma_f32_16x16x32_bf16(af1.s8, S.h3, acc1[3], 0, 0, 0); \
    acc0[4] = __builtin_amdgcn_mfma_f32_16x16x32_bf16(af0.s8, S.h4, acc0[4], 0, 0, 0); \
    acc1[4] = __builtin_amdgcn_mfma_f32_16x16x32_bf16(af1.s8, S.h4, acc1[4], 0, 0, 0); \
    acc0[5] = __builtin_amdgcn_mfma_f32_16x16x32_bf16(af0.s8, S.h5, acc0[5], 0, 0, 0); \
    acc1[5] = __builtin_amdgcn_mfma_f32_16x16x32_bf16(af1.s8, S.h5, acc1[5], 0, 0, 0); \
    acc0[6] = __builtin_amdgcn_mfma_f32_16x16x32_bf16(af0.s8, S.h6, acc0[6], 0, 0, 0); \
    acc1[6] = __builtin_amdgcn_mfma_f32_16x16x32_bf16(af1.s8, S.h6, acc1[6], 0, 0, 0); \
    acc0[7] = __builtin_amdgcn_mfma_f32_16x16x32_bf16(af0.s8, S.h7, acc0[7], 0, 0, 0); \
    acc1[7] = __builtin_amdgcn_mfma_f32_16x16x32_bf16(af1.s8, S.h7, acc1[7], 0, 0, 0); \
  }

__global__ __launch_bounds__(512, 2) void k_att(const float* __restrict__ sg,
                                                const float* __restrict__ tg,
                                                const float* __restrict__ c2g,
                                                const u32* __restrict__ maskT,
                                                const u16* __restrict__ hb,
                                                float* __restrict__ att,
                                                float* __restrict__ hp) {
  __shared__ float hsum[32 * 132];
  const int tid = threadIdx.x;
  const int w = tid >> 6, lane = tid & 63;
  const int arow = lane & 15, kg = lane >> 4;
  const int R0 = blockIdx.x << 5;
  const int w8 = w * 8;

  for (int i = tid; i < 32 * 132; i += 512) hsum[i] = 0.f;
  __syncthreads();

  const int row0 = R0 + arow, row1 = row0 + 16;
  const float s0 = sg[row0], s1 = sg[row1];
  const float c0 = c2g[row0], c1r = c2g[row1];

  f32x4 acc0[8], acc1[8];
#pragma unroll
  for (int i = 0; i < 8; ++i) {
    acc0[i] = (f32x4){0.f, 0.f, 0.f, 0.f};
    acc1[i] = (f32x4){0.f, 0.f, 0.f, 0.f};
  }

  StepT A, B;
  LOADSTEP(0, A);
#pragma unroll
  for (int st = 0; st < 32; ++st) {
    if ((st & 1) == 0) {
      if (st < 31) LOADSTEP(st + 1, B);
      { const StepT& S = A; BODYSTEP(st, S); }
    } else {
      if (st < 31) LOADSTEP(st + 1, A);
      { const StepT& S = B; BODYSTEP(st, S); }
    }
  }

#pragma unroll
  for (int nt = 0; nt < 8; ++nt)
#pragma unroll
    for (int q = 0; q < 4; ++q) {
      atomicAdd(&hsum[(kg * 4 + q) * 132 + nt * 16 + arow], acc0[nt][q]);
      atomicAdd(&hsum[(16 + kg * 4 + q) * 132 + nt * 16 + arow], acc1[nt][q]);
    }
  __syncthreads();
  for (int i = tid; i < 4096; i += 512)
    hp[(size_t)(R0 + (i >> 7)) * FOUT + (i & 127)] = hsum[(i >> 7) * 132 + (i & 127)];
}

extern "C" void kernel_launch(void* const* d_in, const int* in_sizes, int n_in,
                              void* d_out, int out_size, void* d_ws, size_t ws_size,
                              hipStream_t stream) {
  const float* x = (const float*)d_in[0];
  const int* adj = (const int*)d_in[1];
  const float* w = (const float*)d_in[2];
  const float* a = (const float*)d_in[3];
  float* out = (float*)d_out;
  float* att = out;
  float* hp = out + (size_t)NN * NN;
  u16* hb = (u16*)d_ws;                                        // [0, 2MB)
  float* s = (float*)((char*)d_ws + (size_t)2 * 1024 * 1024);
  float* t = s + NN;
  float* c2 = t + NN;
  float* tmax = c2 + NN;
  u32* maskT = (u32*)((char*)d_ws + (size_t)4 * 1024 * 1024);  // [4MB, 12MB)

  k_h<<<256, 256, 0, stream>>>(x, w, a, hb, s, t);
  k_tmax<<<1, 256, 0, stream>>>(t, tmax);
  k_mask<<<512, 1024, 0, stream>>>(adj, s, t, tmax, maskT, c2);
  k_att<<<256, 512, 0, stream>>>(s, t, c2, maskT, hb, att, hp);
}

// Round 7
// 233.023 us; speedup vs baseline: 1.5508x; 1.1409x over previous
//
#include <hip/hip_runtime.h>
#include <hip/hip_bf16.h>

typedef unsigned short u16;
typedef unsigned int u32;
typedef __attribute__((ext_vector_type(8))) short short8;
typedef __attribute__((ext_vector_type(4))) float f32x4;

#define NN 8192
#define FIN 512
#define FOUT 128
#define NEG 0.2f
#define L2E 1.44269504088896340736f
#define EXP2(x) __builtin_amdgcn_exp2f(x)
#define LOG2(x) __builtin_amdgcn_logf(x)

__device__ __forceinline__ u16 f2bf(float f) {
  u32 u = __builtin_bit_cast(u32, f);
  u32 r = (u + 0x7fffu + ((u >> 16) & 1u)) >> 16;
  return (u16)r;
}

// K1: h = x @ w. Emits hb (bf16, blocked-transposed-XOR-swizzled:
// hb[chunk][n][jj ^ ((n&7)<<3)], jj=row%128) and s,t scores directly.
__global__ __launch_bounds__(256) void k_h(const float* __restrict__ x,
                                           const float* __restrict__ w,
                                           const float* __restrict__ av,
                                           u16* __restrict__ hb,
                                           float* __restrict__ sg,
                                           float* __restrict__ tgo) {
  __shared__ float xs[32][68];
  __shared__ float ws_[64][128];
  const int t = threadIdx.x;
  const int r0 = blockIdx.x * 32;
  const int r = t >> 3;
  const int cq = (t & 7) * 4;
  float acc[4][4] = {};
  for (int kc = 0; kc < FIN; kc += 64) {
    __syncthreads();
    {
      const int rr = t >> 3, cc = (t & 7) * 8;
      const float4* src = (const float4*)(x + (size_t)(r0 + rr) * FIN + kc + cc);
      *(float4*)&xs[rr][cc] = src[0];
      *(float4*)&xs[rr][cc + 4] = src[1];
    }
#pragma unroll
    for (int i = 0; i < 8; ++i) {
      const int off = i * 1024 + t * 4;
      const int wr = off >> 7, wc = off & 127;
      *(float4*)&ws_[wr][wc] = *(const float4*)(w + (size_t)(kc + wr) * FOUT + wc);
    }
    __syncthreads();
    for (int kk = 0; kk < 64; ++kk) {
      const float xv = xs[r][kk];
#pragma unroll
      for (int g = 0; g < 4; ++g) {
        const float4 wv = *(const float4*)&ws_[kk][cq + 32 * g];
        acc[g][0] = fmaf(xv, wv.x, acc[g][0]);
        acc[g][1] = fmaf(xv, wv.y, acc[g][1]);
        acc[g][2] = fmaf(xv, wv.z, acc[g][2]);
        acc[g][3] = fmaf(xv, wv.w, acc[g][3]);
      }
    }
  }
  const int rg = r0 + r;
  const int ch = rg >> 7;
  const int jj = rg & 127;
  float sp = 0.f, tp = 0.f;
#pragma unroll
  for (int g = 0; g < 4; ++g) {
#pragma unroll
    for (int e = 0; e < 4; ++e) {
      const int n = cq + 32 * g + e;
      const float v = acc[g][e];
      hb[(size_t)ch * 16384 + n * 128 + (jj ^ ((n & 7) << 3))] = f2bf(v);
      sp = fmaf(v, av[n], sp);
      tp = fmaf(v, av[FOUT + n], tp);
    }
  }
#pragma unroll
  for (int d = 1; d < 8; d <<= 1) {
    sp += __shfl_xor(sp, d);
    tp += __shfl_xor(tp, d);
  }
  if ((t & 7) == 0) { sg[rg] = sp; tgo[rg] = tp; }
}

// K2: tmax = max(t)
__global__ __launch_bounds__(256) void k_tmax(const float* __restrict__ t,
                                              float* __restrict__ tmax) {
  __shared__ float red[256];
  float m = -1e30f;
  for (int i = threadIdx.x; i < NN; i += 256) m = fmaxf(m, t[i]);
  red[threadIdx.x] = m;
  __syncthreads();
  for (int s2 = 128; s2 > 0; s2 >>= 1) {
    if (threadIdx.x < s2) red[threadIdx.x] = fmaxf(red[threadIdx.x], red[threadIdx.x + s2]);
    __syncthreads();
  }
  if (threadIdx.x == 0) tmax[0] = red[0];
}

// K3: fused attention. Block = 16 rows, 1024 thr (16 waves), grid 512
// -> 2 blocks/CU, 32 waves/CU (100% occupancy), VGPR ~50.
// Pass A: wave w streams adj row r0+w ONCE -> mask bits in LDS + denom;
//         folded constant c2 = -(m*log2e + log2 l), m = lrelu(s+tmax) bound.
// Pass B: 64 chunks of 128 cols; double-buffered P-tile (bf16, XOR-swz):
//         per iter ONE barrier; softmax(c+1)+row-contiguous att stores
//         overlap MFMA(c). 16 waves = 8 col-groups x 2 K-halves; h' merged
//         once via LDS atomicAdd.
__global__ __launch_bounds__(1024) void k_attn(const int* __restrict__ adj,
                                               const float* __restrict__ sg,
                                               const float* __restrict__ tg,
                                               const float* __restrict__ tmaxp,
                                               const u16* __restrict__ hb,
                                               float* __restrict__ att,
                                               float* __restrict__ hp) {
  __shared__ u32 mask[16 * 256];      // 16 KB adj bits
  __shared__ u16 pl[2][16 * 128];     // 8 KB P-tile double buffer
  __shared__ float hsum[16 * 132];    // 8.25 KB h' accumulator
  __shared__ float s_s[16], s_c2[16], s_l[16];
  const int tid = threadIdx.x;
  const int w = tid >> 6, lane = tid & 63;
  const int r0 = blockIdx.x << 4;
  const int row = r0 + w;             // pass A: wave w owns this row

  for (int i = tid; i < 16 * 132; i += 1024) hsum[i] = 0.f;

  // ---- Pass A ----
  const float sv = sg[row];
  const float vm = sv + tmaxp[0];
  const float m = fmaxf(vm, NEG * vm);   // lrelu monotone upper bound
  const float m2 = m * L2E;
  const int4* ap = (const int4*)(adj + (size_t)row * NN);
  float sum = 0.f;
#pragma unroll 4
  for (int it = 0; it < 32; ++it) {
    const int4 a0 = ap[it * 64 + lane];
    const float4 tv = *(const float4*)(tg + it * 256 + lane * 4);
    u32 nib = 0u;
    float e, p, sm = 0.f;
    e = sv + tv.x; e = fmaxf(e, NEG * e); p = EXP2(fmaf(e, L2E, -m2)); sm += (a0.x > 0) ? p : 0.f; nib |= (a0.x > 0) ? 1u : 0u;
    e = sv + tv.y; e = fmaxf(e, NEG * e); p = EXP2(fmaf(e, L2E, -m2)); sm += (a0.y > 0) ? p : 0.f; nib |= (a0.y > 0) ? 2u : 0u;
    e = sv + tv.z; e = fmaxf(e, NEG * e); p = EXP2(fmaf(e, L2E, -m2)); sm += (a0.z > 0) ? p : 0.f; nib |= (a0.z > 0) ? 4u : 0u;
    e = sv + tv.w; e = fmaxf(e, NEG * e); p = EXP2(fmaf(e, L2E, -m2)); sm += (a0.w > 0) ? p : 0.f; nib |= (a0.w > 0) ? 8u : 0u;
    sum += sm;
    u32 v0 = nib;
    v0 |= __shfl_xor(v0, 1) << 4;
    v0 |= __shfl_xor(v0, 2) << 8;
    v0 |= __shfl_xor(v0, 4) << 16;
    if ((lane & 7) == 0) mask[w * 256 + it * 8 + (lane >> 3)] = v0;
  }
#pragma unroll
  for (int d = 1; d < 64; d <<= 1) sum += __shfl_xor(sum, d);
  if (lane == 0) { s_l[w] = sum; s_s[w] = sv; }
  __syncthreads();
  if (tid < 16) {
    const float s2v = s_s[tid] + tmaxp[0];
    const float mm = fmaxf(s2v, NEG * s2v);
    s_c2[tid] = -(mm * L2E + LOG2(s_l[tid]));
  }
  __syncthreads();

  // ---- Pass B ----
  const float sR = s_s[w], c2R = s_c2[w];
  const int swzW = (w & 7) << 3;
  const int arow = lane & 15, kg = lane >> 4;
  const int bcol = 16 * (w & 7) + arow;   // output col of h'
  const int ksbase = (w >> 3) * 2;        // this wave's 2 of 4 K-slices
  const int swzB = (bcol & 7) << 3;
  const int swzA = (arow & 7) << 3;
  f32x4 acc = {0.f, 0.f, 0.f, 0.f};

#define COMPUTE(c, buf)                                                        \
  {                                                                            \
    const int j0 = (c) << 7;                                                   \
    const float2 tv = *(const float2*)(tg + j0 + 2 * lane);                    \
    const u32 wd = mask[w * 256 + (c) * 4 + (lane >> 4)];                      \
    const int sh0 = (2 * lane) & 31;                                           \
    const u32 b0 = (wd >> sh0) & 1u, b1 = (wd >> (sh0 + 1)) & 1u;              \
    float e0 = sR + tv.x; e0 = fmaxf(e0, NEG * e0);                            \
    float e1 = sR + tv.y; e1 = fmaxf(e1, NEG * e1);                            \
    const float p0 = b0 ? EXP2(fmaf(e0, L2E, c2R)) : 0.f;                      \
    const float p1 = b1 ? EXP2(fmaf(e1, L2E, c2R)) : 0.f;                      \
    float2 o; o.x = p0; o.y = p1;                                              \
    *(float2*)(att + (size_t)row * NN + j0 + 2 * lane) = o;                    \
    const u32 pk = (u32)f2bf(p0) | ((u32)f2bf(p1) << 16);                      \
    *(u32*)&pl[buf][w * 128 + ((2 * lane) ^ swzW)] = pk;                       \
  }

  COMPUTE(0, 0);
  for (int c = 0; c < 64; ++c) {
    __syncthreads();
    if (c < 63) COMPUTE(c + 1, (c + 1) & 1);
    {
      const u16* hc = hb + (size_t)c * 16384 + (size_t)bcol * 128;
      const u16* pb = &pl[c & 1][0];
#pragma unroll
      for (int k2 = 0; k2 < 2; ++k2) {
        const int ko = (ksbase + k2) * 32 + kg * 8;
        const short8 bf = *(const short8*)(hc + (ko ^ swzB));
        const short8 af = *(const short8*)(pb + arow * 128 + (ko ^ swzA));
        acc = __builtin_amdgcn_mfma_f32_16x16x32_bf16(af, bf, acc, 0, 0, 0);
      }
    }
  }
#undef COMPUTE

  // merge the two K-half partials and store h'
#pragma unroll
  for (int q = 0; q < 4; ++q)
    atomicAdd(&hsum[(kg * 4 + q) * 132 + bcol], acc[q]);
  __syncthreads();
  for (int i = tid; i < 2048; i += 1024)
    hp[(size_t)(r0 + (i >> 7)) * FOUT + (i & 127)] = hsum[(i >> 7) * 132 + (i & 127)];
}

extern "C" void kernel_launch(void* const* d_in, const int* in_sizes, int n_in,
                              void* d_out, int out_size, void* d_ws, size_t ws_size,
                              hipStream_t stream) {
  const float* x = (const float*)d_in[0];
  const int* adj = (const int*)d_in[1];
  const float* w = (const float*)d_in[2];
  const float* a = (const float*)d_in[3];
  float* out = (float*)d_out;
  float* att = out;
  float* hp = out + (size_t)NN * NN;
  u16* hb = (u16*)d_ws;                                        // [0, 2MB)
  float* s = (float*)((char*)d_ws + (size_t)2 * 1024 * 1024);
  float* t = s + NN;
  float* tmax = t + NN;

  k_h<<<256, 256, 0, stream>>>(x, w, a, hb, s, t);
  k_tmax<<<1, 256, 0, stream>>>(t, tmax);
  k_attn<<<512, 1024, 0, stream>>>(adj, s, t, tmax, hb, att, hp);
}